// Round 4
// baseline (705.958 us; speedup 1.0000x reference)
//
#include <hip/hip_runtime.h>
#include <math.h>

#define HH 64
#define SCAN_B 1024

// ---------------- CSR build ----------------

__global__ void k_zero_int(int* __restrict__ p, int n) {
    int i = blockIdx.x * blockDim.x + threadIdx.x;
    if (i < n) p[i] = 0;
}

__global__ void k_count(const int* __restrict__ col, int E, int* __restrict__ cnt) {
    int e = blockIdx.x * blockDim.x + threadIdx.x;
    if (e < E) atomicAdd(&cnt[col[e]], 1);
}

__global__ void k_scan_reduce(const int* __restrict__ cnt, int n, int* __restrict__ partial) {
    int i = blockIdx.x * SCAN_B + threadIdx.x;
    int v = (i < n) ? cnt[i] : 0;
#pragma unroll
    for (int off = 1; off < 64; off <<= 1) v += __shfl_xor(v, off, 64);
    __shared__ int ws[SCAN_B / 64];
    if ((threadIdx.x & 63) == 0) ws[threadIdx.x >> 6] = v;
    __syncthreads();
    if (threadIdx.x == 0) {
        int s = 0;
#pragma unroll
        for (int j = 0; j < SCAN_B / 64; ++j) s += ws[j];
        partial[blockIdx.x] = s;
    }
}

__global__ void k_scan_partials(int* __restrict__ partial, int nb, int* __restrict__ rowptr, int n) {
    __shared__ int buf[1024];
    int tid = threadIdx.x;
    int orig = (tid < nb) ? partial[tid] : 0;
    buf[tid] = orig;
    __syncthreads();
#pragma unroll
    for (int off = 1; off < 1024; off <<= 1) {
        int t = (tid >= off) ? buf[tid - off] : 0;
        __syncthreads();
        buf[tid] += t;
        __syncthreads();
    }
    if (tid < nb) partial[tid] = buf[tid] - orig;
    if (tid == nb - 1) rowptr[n] = buf[tid];
}

__global__ void k_scan_apply(const int* __restrict__ cnt, const int* __restrict__ partial,
                             int n, int* __restrict__ rowptr, int* __restrict__ fill,
                             float* __restrict__ dinv) {
    __shared__ int buf[SCAN_B];
    int tid = threadIdx.x;
    int i = blockIdx.x * SCAN_B + tid;
    int orig = (i < n) ? cnt[i] : 0;
    buf[tid] = orig;
    __syncthreads();
#pragma unroll
    for (int off = 1; off < SCAN_B; off <<= 1) {
        int t = (tid >= off) ? buf[tid - off] : 0;
        __syncthreads();
        buf[tid] += t;
        __syncthreads();
    }
    if (i < n) {
        int excl = buf[tid] - orig + partial[blockIdx.x];
        rowptr[i] = excl;
        fill[i]   = excl;
        dinv[i]   = rsqrtf((float)(orig + 1));
    }
}

__global__ void k_fill(const int* __restrict__ row, const int* __restrict__ col,
                       const float* __restrict__ dinv, int E,
                       int* __restrict__ fill, int* __restrict__ csr_src,
                       float* __restrict__ csr_w) {
    int e = blockIdx.x * blockDim.x + threadIdx.x;
    if (e >= E) return;
    int r = row[e], c = col[e];
    int dst = atomicAdd(&fill[c], 1);
    csr_src[dst] = r;
    csr_w[dst]   = dinv[r] * dinv[c];
}

// ---------------- dense transform: register-tiled LDS GEMM ----------------
// 64 nodes x 64 feats per 256-thread block; each thread owns 4 nodes x 4 feats
// (16 independent fma chains). W and x-tile staged in LDS.
template<int FIN>
__global__ __launch_bounds__(256) void k_gemm_tile(const float* __restrict__ x,
                                                   const float* __restrict__ W,
                                                   float* __restrict__ lin, int n) {
    constexpr int PAD = 4;                   // break stride%32==0 bank aliasing
    __shared__ __align__(16) float xs[64][FIN + PAD];
    __shared__ __align__(16) float Ws[FIN][HH];
    const int tid = threadIdx.x;
    const int tx = tid & 15;                 // feature group (4 feats)
    const int ty = tid >> 4;                 // node group (4 nodes)
    const int node0 = blockIdx.x * 64;

    // stage W (FIN*64 floats), float4, coalesced
#pragma unroll
    for (int i = tid * 4; i < FIN * HH; i += 256 * 4)
        *(float4*)&Ws[0][i] = *(const float4*)&W[i];

    // stage x tile (64*FIN floats), float4, coalesced global reads
#pragma unroll
    for (int idx = tid * 4; idx < 64 * FIN; idx += 256 * 4) {
        int r = idx / FIN, c = idx % FIN;
        float4 v = make_float4(0.f, 0.f, 0.f, 0.f);
        if (node0 + r < n) v = *(const float4*)&x[(size_t)(node0 + r) * FIN + c];
        *(float4*)&xs[r][c] = v;
    }
    __syncthreads();

    float acc[4][4] = {};
#pragma unroll
    for (int k = 0; k < FIN; k += 4) {
        float a[4][4], b[4][4];
#pragma unroll
        for (int i = 0; i < 4; ++i) *(float4*)a[i] = *(const float4*)&xs[ty * 4 + i][k];
#pragma unroll
        for (int j = 0; j < 4; ++j) *(float4*)b[j] = *(const float4*)&Ws[k + j][tx * 4];
#pragma unroll
        for (int i = 0; i < 4; ++i)
#pragma unroll
            for (int kk = 0; kk < 4; ++kk)
#pragma unroll
                for (int f = 0; f < 4; ++f)
                    acc[i][f] = fmaf(a[i][kk], b[kk][f], acc[i][f]);
    }

#pragma unroll
    for (int i = 0; i < 4; ++i) {
        int node = node0 + ty * 4 + i;
        if (node < n) *(float4*)&lin[(size_t)node * HH + tx * 4] = *(float4*)acc[i];
    }
}

// ---------------- gather aggregation + bias + L2norm + ReLU ----------------
__global__ void k_gather(const float* __restrict__ lin, const int* __restrict__ csr_src,
                         const float* __restrict__ csr_w, const int* __restrict__ rowptr,
                         const float* __restrict__ dinv, const float* __restrict__ b,
                         float* __restrict__ hout, int n) {
    int node = blockIdx.x * (blockDim.x >> 6) + (threadIdx.x >> 6);
    int lane = threadIdx.x & 63;
    if (node >= n) return;
    int start = rowptr[node], end = rowptr[node + 1];
    float di = dinv[node];
    float acc0 = di * di * lin[(size_t)node * HH + lane];   // self-loop
    float acc1 = 0.f;
    for (int base = start; base < end; base += 64) {
        int m = end - base; if (m > 64) m = 64;
        int   sv = (base + lane < end) ? csr_src[base + lane] : 0;
        float wv = (base + lane < end) ? csr_w[base + lane]   : 0.f;
        int j = 0;
        for (; j + 1 < m; j += 2) {
            int   s0 = __shfl(sv, j, 64);     float w0 = __shfl(wv, j, 64);
            int   s1 = __shfl(sv, j + 1, 64); float w1 = __shfl(wv, j + 1, 64);
            acc0 = fmaf(w0, lin[(size_t)s0 * HH + lane], acc0);
            acc1 = fmaf(w1, lin[(size_t)s1 * HH + lane], acc1);
        }
        if (j < m) {
            int s0 = __shfl(sv, j, 64); float w0 = __shfl(wv, j, 64);
            acc0 = fmaf(w0, lin[(size_t)s0 * HH + lane], acc0);
        }
    }
    float v = acc0 + acc1 + b[lane];
    float ss = v * v;
#pragma unroll
    for (int off = 1; off < 64; off <<= 1) ss += __shfl_xor(ss, off, 64);
    v = v / fmaxf(sqrtf(ss), 1e-12f);
    hout[(size_t)node * HH + lane] = fmaxf(v, 0.f);
}

// ---------------- pool + classifier + softmax ----------------
__global__ void k_final(const float* __restrict__ node_emb, const int* __restrict__ batch,
                        const float* __restrict__ Wm, const float* __restrict__ bm,
                        float* __restrict__ logits, float* __restrict__ probs,
                        float* __restrict__ graph_emb, int n) {
    int g = blockIdx.x;
    int lane = threadIdx.x;
    int lo = 0, hi = n;
    while (lo < hi) { int mid = (lo + hi) >> 1; if (batch[mid] < g) lo = mid + 1; else hi = mid; }
    int start = lo;
    lo = start; hi = n;
    while (lo < hi) { int mid = (lo + hi) >> 1; if (batch[mid] < g + 1) lo = mid + 1; else hi = mid; }
    int end = lo;

    float s = 0.f;
    for (int node = start; node < end; ++node) s += node_emb[(size_t)node * HH + lane];
    float cnt = (float)(end - start);
    float mean = s / fmaxf(cnt, 1.0f);
    graph_emb[(size_t)g * HH + lane] = mean;

    __shared__ float semb[HH];
    __shared__ float slog[16];
    semb[lane] = mean;
    __syncthreads();
    if (lane < 10) {
        float acc = bm[lane];
        for (int k = 0; k < HH; ++k) acc = fmaf(semb[k], Wm[k * 10 + lane], acc);
        slog[lane] = acc;
    }
    __syncthreads();
    if (lane < 10) {
        float mx = -1e30f;
        for (int j = 0; j < 10; ++j) mx = fmaxf(mx, slog[j]);
        float den = 0.f;
        for (int j = 0; j < 10; ++j) den += __expf(slog[j] - mx);
        float lg = slog[lane];
        logits[g * 10 + lane] = lg;
        probs[g * 10 + lane] = __expf(lg - mx) / den;
    }
}

// ---------------- launch ----------------

extern "C" void kernel_launch(void* const* d_in, const int* in_sizes, int n_in,
                              void* d_out, int out_size, void* d_ws, size_t ws_size,
                              hipStream_t stream) {
    const float* x     = (const float*)d_in[0];
    const int*   ei    = (const int*)  d_in[1];
    const int*   batch = (const int*)  d_in[2];
    const float* W1 = (const float*)d_in[3];  const float* b1 = (const float*)d_in[4];
    const float* W2 = (const float*)d_in[5];  const float* b2 = (const float*)d_in[6];
    const float* W3 = (const float*)d_in[7];  const float* b3 = (const float*)d_in[8];
    const float* Wm = (const float*)d_in[9];  const float* bm = (const float*)d_in[10];

    const int N = in_sizes[2];
    const int E = in_sizes[1] / 2;
    const int G = (out_size - N * HH) / (2 * 10 + HH);

    const int* row = ei;
    const int* col = ei + E;

    float* out       = (float*)d_out;
    float* logits    = out;
    float* probs     = out + (size_t)G * 10;
    float* node_emb  = out + (size_t)2 * G * 10;
    float* graph_emb = node_emb + (size_t)N * HH;

    char* w = (char*)d_ws;
    auto alloc = [&](size_t bytes) { char* p = w; w += (bytes + 255) & ~(size_t)255; return p; };
    float* dinv    = (float*)alloc((size_t)N * 4);
    int*   cnt     = (int*)  alloc((size_t)N * 4);
    int*   rowptr  = (int*)  alloc(((size_t)N + 1) * 4);
    int*   fill    = (int*)  alloc((size_t)N * 4);
    int*   partial = (int*)  alloc(1024 * 4);
    int*   csr_src = (int*)  alloc((size_t)E * 4);
    float* csr_w   = (float*)alloc((size_t)E * 4);
    float* lin     = (float*)alloc((size_t)N * HH * 4);
    float* hbuf    = (float*)alloc((size_t)N * HH * 4);

    const int B = 256;
    dim3 blk(B);
    int node_blocks = (N + 3) / 4;
    int gemm_blocks = (N + 63) / 64;
    int nB = (N + B - 1) / B;
    int eB = (E + B - 1) / B;
    int scanB = (N + SCAN_B - 1) / SCAN_B;

    // CSR build + normalization
    k_zero_int<<<nB, blk, 0, stream>>>(cnt, N);
    k_count<<<eB, blk, 0, stream>>>(col, E, cnt);
    k_scan_reduce<<<scanB, dim3(SCAN_B), 0, stream>>>(cnt, N, partial);
    k_scan_partials<<<1, dim3(1024), 0, stream>>>(partial, scanB, rowptr, N);
    k_scan_apply<<<scanB, dim3(SCAN_B), 0, stream>>>(cnt, partial, N, rowptr, fill, dinv);
    k_fill<<<eB, blk, 0, stream>>>(row, col, dinv, E, fill, csr_src, csr_w);

    // layer 1 (FIN=128)
    k_gemm_tile<128><<<gemm_blocks, blk, 0, stream>>>(x, W1, lin, N);
    k_gather<<<node_blocks, blk, 0, stream>>>(lin, csr_src, csr_w, rowptr, dinv, b1, hbuf, N);
    // layer 2
    k_gemm_tile<64><<<gemm_blocks, blk, 0, stream>>>(hbuf, W2, lin, N);
    k_gather<<<node_blocks, blk, 0, stream>>>(lin, csr_src, csr_w, rowptr, dinv, b2, hbuf, N);
    // layer 3 -> node_emb
    k_gemm_tile<64><<<gemm_blocks, blk, 0, stream>>>(hbuf, W3, lin, N);
    k_gather<<<node_blocks, blk, 0, stream>>>(lin, csr_src, csr_w, rowptr, dinv, b3, node_emb, N);

    // pool + classifier
    k_final<<<G, dim3(64), 0, stream>>>(node_emb, batch, Wm, bm, logits, probs, graph_emb, N);
}

// Round 5
// 419.953 us; speedup vs baseline: 1.6810x; 1.6810x over previous
//
#include <hip/hip_runtime.h>
#include <math.h>

#define HH 64
#define SCAN_B 1024

// ---------------- CSR build ----------------

__global__ void k_zero_int(int* __restrict__ p, int n) {
    int i = blockIdx.x * blockDim.x + threadIdx.x;
    if (i < n) p[i] = 0;
}

__global__ void k_count(const int* __restrict__ col, int E, int* __restrict__ cnt) {
    int e = blockIdx.x * blockDim.x + threadIdx.x;
    if (e < E) atomicAdd(&cnt[col[e]], 1);
}

__global__ void k_scan_reduce(const int* __restrict__ cnt, int n, int* __restrict__ partial) {
    int i = blockIdx.x * SCAN_B + threadIdx.x;
    int v = (i < n) ? cnt[i] : 0;
#pragma unroll
    for (int off = 1; off < 64; off <<= 1) v += __shfl_xor(v, off, 64);
    __shared__ int ws[SCAN_B / 64];
    if ((threadIdx.x & 63) == 0) ws[threadIdx.x >> 6] = v;
    __syncthreads();
    if (threadIdx.x == 0) {
        int s = 0;
#pragma unroll
        for (int j = 0; j < SCAN_B / 64; ++j) s += ws[j];
        partial[blockIdx.x] = s;
    }
}

__global__ void k_scan_partials(int* __restrict__ partial, int nb, int* __restrict__ rowptr, int n) {
    __shared__ int buf[1024];
    int tid = threadIdx.x;
    int orig = (tid < nb) ? partial[tid] : 0;
    buf[tid] = orig;
    __syncthreads();
#pragma unroll
    for (int off = 1; off < 1024; off <<= 1) {
        int t = (tid >= off) ? buf[tid - off] : 0;
        __syncthreads();
        buf[tid] += t;
        __syncthreads();
    }
    if (tid < nb) partial[tid] = buf[tid] - orig;
    if (tid == nb - 1) rowptr[n] = buf[tid];
}

__global__ void k_scan_apply(const int* __restrict__ cnt, const int* __restrict__ partial,
                             int n, int* __restrict__ rowptr, int* __restrict__ fill,
                             float* __restrict__ dinv) {
    __shared__ int buf[SCAN_B];
    int tid = threadIdx.x;
    int i = blockIdx.x * SCAN_B + tid;
    int orig = (i < n) ? cnt[i] : 0;
    buf[tid] = orig;
    __syncthreads();
#pragma unroll
    for (int off = 1; off < SCAN_B; off <<= 1) {
        int t = (tid >= off) ? buf[tid - off] : 0;
        __syncthreads();
        buf[tid] += t;
        __syncthreads();
    }
    if (i < n) {
        int excl = buf[tid] - orig + partial[blockIdx.x];
        rowptr[i] = excl;
        fill[i]   = excl;
        dinv[i]   = rsqrtf((float)(orig + 1));
    }
}

__global__ void k_fill(const int* __restrict__ row, const int* __restrict__ col,
                       const float* __restrict__ dinv, int E,
                       int* __restrict__ fill, int* __restrict__ csr_src,
                       float* __restrict__ csr_w) {
    int e = blockIdx.x * blockDim.x + threadIdx.x;
    if (e >= E) return;
    int r = row[e], c = col[e];
    int dst = atomicAdd(&fill[c], 1);
    csr_src[dst] = r;
    csr_w[dst]   = dinv[r] * dinv[c];
}

// ---------------- dense transform: k-chunked register-tiled GEMM ----------------
// 64 nodes x 64 feats per 256-thread block; thread owns 4 nodes x 4 feats.
// W fully in LDS; x staged transposed in 32-wide k-chunks (xs_t[k][node]).
// Inner loop: 2x ds_read_b128 + 16 fma per k. VGPR budget ~50 (no spill).
template<int FIN>
__global__ __launch_bounds__(256, 4) void k_gemm2(const float* __restrict__ x,
                                                  const float* __restrict__ W,
                                                  float* __restrict__ lin, int n) {
    constexpr int KC = 32;
    constexpr int XS = 68;   // stride: 16B-aligned rows, 4-way-max banks on write, CF reads
    __shared__ __align__(16) float Ws[FIN][HH];
    __shared__ __align__(16) float xs_t[KC][XS];
    const int tid = threadIdx.x;
    const int tx = tid & 15;              // feature group (4 feats)
    const int ty = tid >> 4;              // node group (4 nodes)
    const int node0 = blockIdx.x * 64;

    // stage W (FIN*64 floats), float4, coalesced
    for (int i = tid * 4; i < FIN * HH; i += 1024)
        *(float4*)&Ws[0][i] = *(const float4*)&W[i];

    float acc[4][4] = {};

    const int rr0 = tid >> 3;             // 0..31
    const int cc  = (tid & 7) * 4;        // 0,4,...,28

    for (int kc = 0; kc < FIN; kc += KC) {
        __syncthreads();                  // xs_t reads of prev chunk done (also covers Ws 1st iter)
        // stage x chunk transposed: xs_t[k][node]
        for (int rr = rr0; rr < 64; rr += 32) {
            float4 v = make_float4(0.f, 0.f, 0.f, 0.f);
            if (node0 + rr < n) v = *(const float4*)&x[(size_t)(node0 + rr) * FIN + kc + cc];
            xs_t[cc + 0][rr] = v.x;
            xs_t[cc + 1][rr] = v.y;
            xs_t[cc + 2][rr] = v.z;
            xs_t[cc + 3][rr] = v.w;
        }
        __syncthreads();
#pragma unroll 4
        for (int k = 0; k < KC; ++k) {
            float4 a4 = *(const float4*)&xs_t[k][ty * 4];
            float4 b4 = *(const float4*)&Ws[kc + k][tx * 4];
            acc[0][0] = fmaf(a4.x, b4.x, acc[0][0]);
            acc[0][1] = fmaf(a4.x, b4.y, acc[0][1]);
            acc[0][2] = fmaf(a4.x, b4.z, acc[0][2]);
            acc[0][3] = fmaf(a4.x, b4.w, acc[0][3]);
            acc[1][0] = fmaf(a4.y, b4.x, acc[1][0]);
            acc[1][1] = fmaf(a4.y, b4.y, acc[1][1]);
            acc[1][2] = fmaf(a4.y, b4.z, acc[1][2]);
            acc[1][3] = fmaf(a4.y, b4.w, acc[1][3]);
            acc[2][0] = fmaf(a4.z, b4.x, acc[2][0]);
            acc[2][1] = fmaf(a4.z, b4.y, acc[2][1]);
            acc[2][2] = fmaf(a4.z, b4.z, acc[2][2]);
            acc[2][3] = fmaf(a4.z, b4.w, acc[2][3]);
            acc[3][0] = fmaf(a4.w, b4.x, acc[3][0]);
            acc[3][1] = fmaf(a4.w, b4.y, acc[3][1]);
            acc[3][2] = fmaf(a4.w, b4.z, acc[3][2]);
            acc[3][3] = fmaf(a4.w, b4.w, acc[3][3]);
        }
    }

#pragma unroll
    for (int i = 0; i < 4; ++i) {
        int node = node0 + ty * 4 + i;
        if (node < n) *(float4*)&lin[(size_t)node * HH + tx * 4] = *(float4*)acc[i];
    }
}

// ---------------- gather aggregation + bias + L2norm + ReLU ----------------
__global__ void k_gather(const float* __restrict__ lin, const int* __restrict__ csr_src,
                         const float* __restrict__ csr_w, const int* __restrict__ rowptr,
                         const float* __restrict__ dinv, const float* __restrict__ b,
                         float* __restrict__ hout, int n) {
    int node = blockIdx.x * (blockDim.x >> 6) + (threadIdx.x >> 6);
    int lane = threadIdx.x & 63;
    if (node >= n) return;
    int start = rowptr[node], end = rowptr[node + 1];
    float di = dinv[node];
    float acc0 = di * di * lin[(size_t)node * HH + lane];   // self-loop
    float acc1 = 0.f;
    for (int base = start; base < end; base += 64) {
        int m = end - base; if (m > 64) m = 64;
        int   sv = (base + lane < end) ? csr_src[base + lane] : 0;
        float wv = (base + lane < end) ? csr_w[base + lane]   : 0.f;
        int j = 0;
        for (; j + 1 < m; j += 2) {
            int   s0 = __shfl(sv, j, 64);     float w0 = __shfl(wv, j, 64);
            int   s1 = __shfl(sv, j + 1, 64); float w1 = __shfl(wv, j + 1, 64);
            acc0 = fmaf(w0, lin[(size_t)s0 * HH + lane], acc0);
            acc1 = fmaf(w1, lin[(size_t)s1 * HH + lane], acc1);
        }
        if (j < m) {
            int s0 = __shfl(sv, j, 64); float w0 = __shfl(wv, j, 64);
            acc0 = fmaf(w0, lin[(size_t)s0 * HH + lane], acc0);
        }
    }
    float v = acc0 + acc1 + b[lane];
    float ss = v * v;
#pragma unroll
    for (int off = 1; off < 64; off <<= 1) ss += __shfl_xor(ss, off, 64);
    v = v / fmaxf(sqrtf(ss), 1e-12f);
    hout[(size_t)node * HH + lane] = fmaxf(v, 0.f);
}

// ---------------- pool + classifier + softmax ----------------
__global__ void k_final(const float* __restrict__ node_emb, const int* __restrict__ batch,
                        const float* __restrict__ Wm, const float* __restrict__ bm,
                        float* __restrict__ logits, float* __restrict__ probs,
                        float* __restrict__ graph_emb, int n) {
    int g = blockIdx.x;
    int lane = threadIdx.x;
    int lo = 0, hi = n;
    while (lo < hi) { int mid = (lo + hi) >> 1; if (batch[mid] < g) lo = mid + 1; else hi = mid; }
    int start = lo;
    lo = start; hi = n;
    while (lo < hi) { int mid = (lo + hi) >> 1; if (batch[mid] < g + 1) lo = mid + 1; else hi = mid; }
    int end = lo;

    float s = 0.f;
    for (int node = start; node < end; ++node) s += node_emb[(size_t)node * HH + lane];
    float cnt = (float)(end - start);
    float mean = s / fmaxf(cnt, 1.0f);
    graph_emb[(size_t)g * HH + lane] = mean;

    __shared__ float semb[HH];
    __shared__ float slog[16];
    semb[lane] = mean;
    __syncthreads();
    if (lane < 10) {
        float acc = bm[lane];
        for (int k = 0; k < HH; ++k) acc = fmaf(semb[k], Wm[k * 10 + lane], acc);
        slog[lane] = acc;
    }
    __syncthreads();
    if (lane < 10) {
        float mx = -1e30f;
        for (int j = 0; j < 10; ++j) mx = fmaxf(mx, slog[j]);
        float den = 0.f;
        for (int j = 0; j < 10; ++j) den += __expf(slog[j] - mx);
        float lg = slog[lane];
        logits[g * 10 + lane] = lg;
        probs[g * 10 + lane] = __expf(lg - mx) / den;
    }
}

// ---------------- launch ----------------

extern "C" void kernel_launch(void* const* d_in, const int* in_sizes, int n_in,
                              void* d_out, int out_size, void* d_ws, size_t ws_size,
                              hipStream_t stream) {
    const float* x     = (const float*)d_in[0];
    const int*   ei    = (const int*)  d_in[1];
    const int*   batch = (const int*)  d_in[2];
    const float* W1 = (const float*)d_in[3];  const float* b1 = (const float*)d_in[4];
    const float* W2 = (const float*)d_in[5];  const float* b2 = (const float*)d_in[6];
    const float* W3 = (const float*)d_in[7];  const float* b3 = (const float*)d_in[8];
    const float* Wm = (const float*)d_in[9];  const float* bm = (const float*)d_in[10];

    const int N = in_sizes[2];
    const int E = in_sizes[1] / 2;
    const int G = (out_size - N * HH) / (2 * 10 + HH);

    const int* row = ei;
    const int* col = ei + E;

    float* out       = (float*)d_out;
    float* logits    = out;
    float* probs     = out + (size_t)G * 10;
    float* node_emb  = out + (size_t)2 * G * 10;
    float* graph_emb = node_emb + (size_t)N * HH;

    char* w = (char*)d_ws;
    auto alloc = [&](size_t bytes) { char* p = w; w += (bytes + 255) & ~(size_t)255; return p; };
    float* dinv    = (float*)alloc((size_t)N * 4);
    int*   cnt     = (int*)  alloc((size_t)N * 4);
    int*   rowptr  = (int*)  alloc(((size_t)N + 1) * 4);
    int*   fill    = (int*)  alloc((size_t)N * 4);
    int*   partial = (int*)  alloc(1024 * 4);
    int*   csr_src = (int*)  alloc((size_t)E * 4);
    float* csr_w   = (float*)alloc((size_t)E * 4);
    float* lin     = (float*)alloc((size_t)N * HH * 4);
    float* hbuf    = (float*)alloc((size_t)N * HH * 4);

    const int B = 256;
    dim3 blk(B);
    int node_blocks = (N + 3) / 4;
    int gemm_blocks = (N + 63) / 64;
    int nB = (N + B - 1) / B;
    int eB = (E + B - 1) / B;
    int scanB = (N + SCAN_B - 1) / SCAN_B;

    // CSR build + normalization
    k_zero_int<<<nB, blk, 0, stream>>>(cnt, N);
    k_count<<<eB, blk, 0, stream>>>(col, E, cnt);
    k_scan_reduce<<<scanB, dim3(SCAN_B), 0, stream>>>(cnt, N, partial);
    k_scan_partials<<<1, dim3(1024), 0, stream>>>(partial, scanB, rowptr, N);
    k_scan_apply<<<scanB, dim3(SCAN_B), 0, stream>>>(cnt, partial, N, rowptr, fill, dinv);
    k_fill<<<eB, blk, 0, stream>>>(row, col, dinv, E, fill, csr_src, csr_w);

    // layer 1 (FIN=128)
    k_gemm2<128><<<gemm_blocks, blk, 0, stream>>>(x, W1, lin, N);
    k_gather<<<node_blocks, blk, 0, stream>>>(lin, csr_src, csr_w, rowptr, dinv, b1, hbuf, N);
    // layer 2
    k_gemm2<64><<<gemm_blocks, blk, 0, stream>>>(hbuf, W2, lin, N);
    k_gather<<<node_blocks, blk, 0, stream>>>(lin, csr_src, csr_w, rowptr, dinv, b2, hbuf, N);
    // layer 3 -> node_emb
    k_gemm2<64><<<gemm_blocks, blk, 0, stream>>>(hbuf, W3, lin, N);
    k_gather<<<node_blocks, blk, 0, stream>>>(lin, csr_src, csr_w, rowptr, dinv, b3, node_emb, N);

    // pool + classifier
    k_final<<<G, dim3(64), 0, stream>>>(node_emb, batch, Wm, bm, logits, probs, graph_emb, N);
}

// Round 6
// 362.817 us; speedup vs baseline: 1.9458x; 1.1575x over previous
//
#include <hip/hip_runtime.h>
#include <math.h>

#define HH 64
#define SCAN_B 1024

// ---------------- CSR build ----------------

__global__ void k_zero_int(int* __restrict__ p, int n) {
    int i = blockIdx.x * blockDim.x + threadIdx.x;
    if (i < n) p[i] = 0;
}

__global__ void k_zero_float(float* __restrict__ p, int n) {
    int i = blockIdx.x * blockDim.x + threadIdx.x;
    if (i < n) p[i] = 0.f;
}

__global__ void k_count(const int* __restrict__ col, int E, int* __restrict__ cnt) {
    int e = blockIdx.x * blockDim.x + threadIdx.x;
    if (e < E) atomicAdd(&cnt[col[e]], 1);
}

__global__ void k_scan_reduce(const int* __restrict__ cnt, int n, int* __restrict__ partial) {
    int i = blockIdx.x * SCAN_B + threadIdx.x;
    int v = (i < n) ? cnt[i] : 0;
#pragma unroll
    for (int off = 1; off < 64; off <<= 1) v += __shfl_xor(v, off, 64);
    __shared__ int ws[SCAN_B / 64];
    if ((threadIdx.x & 63) == 0) ws[threadIdx.x >> 6] = v;
    __syncthreads();
    if (threadIdx.x == 0) {
        int s = 0;
#pragma unroll
        for (int j = 0; j < SCAN_B / 64; ++j) s += ws[j];
        partial[blockIdx.x] = s;
    }
}

__global__ void k_scan_partials(int* __restrict__ partial, int nb, int* __restrict__ rowptr, int n) {
    __shared__ int buf[1024];
    int tid = threadIdx.x;
    int orig = (tid < nb) ? partial[tid] : 0;
    buf[tid] = orig;
    __syncthreads();
#pragma unroll
    for (int off = 1; off < 1024; off <<= 1) {
        int t = (tid >= off) ? buf[tid - off] : 0;
        __syncthreads();
        buf[tid] += t;
        __syncthreads();
    }
    if (tid < nb) partial[tid] = buf[tid] - orig;
    if (tid == nb - 1) rowptr[n] = buf[tid];
}

__global__ void k_scan_apply(const int* __restrict__ cnt, const int* __restrict__ partial,
                             int n, int* __restrict__ rowptr, int* __restrict__ fill,
                             float* __restrict__ dinv) {
    __shared__ int buf[SCAN_B];
    int tid = threadIdx.x;
    int i = blockIdx.x * SCAN_B + tid;
    int orig = (i < n) ? cnt[i] : 0;
    buf[tid] = orig;
    __syncthreads();
#pragma unroll
    for (int off = 1; off < SCAN_B; off <<= 1) {
        int t = (tid >= off) ? buf[tid - off] : 0;
        __syncthreads();
        buf[tid] += t;
        __syncthreads();
    }
    if (i < n) {
        int excl = buf[tid] - orig + partial[blockIdx.x];
        rowptr[i] = excl;
        fill[i]   = excl;
        dinv[i]   = rsqrtf((float)(orig + 1));
    }
}

__global__ void k_fill(const int* __restrict__ row, const int* __restrict__ col,
                       const float* __restrict__ dinv, int E,
                       int* __restrict__ fill, int* __restrict__ csr_src,
                       float* __restrict__ csr_w) {
    int e = blockIdx.x * blockDim.x + threadIdx.x;
    if (e >= E) return;
    int r = row[e], c = col[e];
    int dst = atomicAdd(&fill[c], 1);
    csr_src[dst] = r;
    csr_w[dst]   = dinv[r] * dinv[c];
}

// ---------------- dense transform: k-chunked register-tiled GEMM ----------------
template<int FIN>
__global__ __launch_bounds__(256, 4) void k_gemm2(const float* __restrict__ x,
                                                  const float* __restrict__ W,
                                                  float* __restrict__ lin, int n) {
    constexpr int KC = 32;
    constexpr int XS = 68;
    __shared__ __align__(16) float Ws[FIN][HH];
    __shared__ __align__(16) float xs_t[KC][XS];
    const int tid = threadIdx.x;
    const int tx = tid & 15;
    const int ty = tid >> 4;
    const int node0 = blockIdx.x * 64;

    for (int i = tid * 4; i < FIN * HH; i += 1024)
        *(float4*)&Ws[0][i] = *(const float4*)&W[i];

    float acc[4][4] = {};

    const int rr0 = tid >> 3;
    const int cc  = (tid & 7) * 4;

    for (int kc = 0; kc < FIN; kc += KC) {
        __syncthreads();
        for (int rr = rr0; rr < 64; rr += 32) {
            float4 v = make_float4(0.f, 0.f, 0.f, 0.f);
            if (node0 + rr < n) v = *(const float4*)&x[(size_t)(node0 + rr) * FIN + kc + cc];
            xs_t[cc + 0][rr] = v.x;
            xs_t[cc + 1][rr] = v.y;
            xs_t[cc + 2][rr] = v.z;
            xs_t[cc + 3][rr] = v.w;
        }
        __syncthreads();
#pragma unroll 4
        for (int k = 0; k < KC; ++k) {
            float4 a4 = *(const float4*)&xs_t[k][ty * 4];
            float4 b4 = *(const float4*)&Ws[kc + k][tx * 4];
            acc[0][0] = fmaf(a4.x, b4.x, acc[0][0]);
            acc[0][1] = fmaf(a4.x, b4.y, acc[0][1]);
            acc[0][2] = fmaf(a4.x, b4.z, acc[0][2]);
            acc[0][3] = fmaf(a4.x, b4.w, acc[0][3]);
            acc[1][0] = fmaf(a4.y, b4.x, acc[1][0]);
            acc[1][1] = fmaf(a4.y, b4.y, acc[1][1]);
            acc[1][2] = fmaf(a4.y, b4.z, acc[1][2]);
            acc[1][3] = fmaf(a4.y, b4.w, acc[1][3]);
            acc[2][0] = fmaf(a4.z, b4.x, acc[2][0]);
            acc[2][1] = fmaf(a4.z, b4.y, acc[2][1]);
            acc[2][2] = fmaf(a4.z, b4.z, acc[2][2]);
            acc[2][3] = fmaf(a4.z, b4.w, acc[2][3]);
            acc[3][0] = fmaf(a4.w, b4.x, acc[3][0]);
            acc[3][1] = fmaf(a4.w, b4.y, acc[3][1]);
            acc[3][2] = fmaf(a4.w, b4.z, acc[3][2]);
            acc[3][3] = fmaf(a4.w, b4.w, acc[3][3]);
        }
    }

#pragma unroll
    for (int i = 0; i < 4; ++i) {
        int node = node0 + ty * 4 + i;
        if (node < n) *(float4*)&lin[(size_t)node * HH + tx * 4] = *(float4*)acc[i];
    }
}

// ---------------- gather aggregation + bias + L2norm + ReLU ----------------
__global__ void k_gather(const float* __restrict__ lin, const int* __restrict__ csr_src,
                         const float* __restrict__ csr_w, const int* __restrict__ rowptr,
                         const float* __restrict__ dinv, const float* __restrict__ b,
                         float* __restrict__ hout, int n) {
    int node = blockIdx.x * (blockDim.x >> 6) + (threadIdx.x >> 6);
    int lane = threadIdx.x & 63;
    if (node >= n) return;
    int start = rowptr[node], end = rowptr[node + 1];
    float di = dinv[node];
    float acc0 = di * di * lin[(size_t)node * HH + lane];   // self-loop
    float acc1 = 0.f;
    for (int base = start; base < end; base += 64) {
        int m = end - base; if (m > 64) m = 64;
        int   sv = (base + lane < end) ? csr_src[base + lane] : 0;
        float wv = (base + lane < end) ? csr_w[base + lane]   : 0.f;
        int j = 0;
        for (; j + 1 < m; j += 2) {
            int   s0 = __shfl(sv, j, 64);     float w0 = __shfl(wv, j, 64);
            int   s1 = __shfl(sv, j + 1, 64); float w1 = __shfl(wv, j + 1, 64);
            acc0 = fmaf(w0, lin[(size_t)s0 * HH + lane], acc0);
            acc1 = fmaf(w1, lin[(size_t)s1 * HH + lane], acc1);
        }
        if (j < m) {
            int s0 = __shfl(sv, j, 64); float w0 = __shfl(wv, j, 64);
            acc0 = fmaf(w0, lin[(size_t)s0 * HH + lane], acc0);
        }
    }
    float v = acc0 + acc1 + b[lane];
    float ss = v * v;
#pragma unroll
    for (int off = 1; off < 64; off <<= 1) ss += __shfl_xor(ss, off, 64);
    v = v / fmaxf(sqrtf(ss), 1e-12f);
    hout[(size_t)node * HH + lane] = fmaxf(v, 0.f);
}

// ---------------- pooling: parallel over nodes ----------------
// 16 nodes per wave; batch sorted -> local accumulate, flush per graph-run.
__global__ __launch_bounds__(256) void k_pool(const float* __restrict__ node_emb,
                                              const int* __restrict__ batch,
                                              float* __restrict__ sums,
                                              float* __restrict__ cnts, int n) {
    const int NPW = 16;
    int wave = blockIdx.x * 4 + (threadIdx.x >> 6);
    int lane = threadIdx.x & 63;
    int start = wave * NPW;
    if (start >= n) return;
    int end = start + NPW; if (end > n) end = n;
    int cur = batch[start];
    float acc = 0.f;
    int runlen = 0;
    for (int node = start; node < end; ++node) {
        int g = batch[node];
        if (g != cur) {
            atomicAdd(&sums[(size_t)cur * HH + lane], acc);
            if (lane == 0) atomicAdd(&cnts[cur], (float)runlen);
            acc = 0.f; runlen = 0; cur = g;
        }
        acc += node_emb[(size_t)node * HH + lane];
        ++runlen;
    }
    atomicAdd(&sums[(size_t)cur * HH + lane], acc);
    if (lane == 0) atomicAdd(&cnts[cur], (float)runlen);
}

// ---------------- classifier + softmax ----------------
__global__ void k_final2(const float* __restrict__ sums, const float* __restrict__ cnts,
                         const float* __restrict__ Wm, const float* __restrict__ bm,
                         float* __restrict__ logits, float* __restrict__ probs,
                         float* __restrict__ graph_emb) {
    int g = blockIdx.x;
    int lane = threadIdx.x;
    float mean = sums[(size_t)g * HH + lane] / fmaxf(cnts[g], 1.0f);
    graph_emb[(size_t)g * HH + lane] = mean;

    __shared__ float semb[HH];
    __shared__ float slog[16];
    semb[lane] = mean;
    __syncthreads();
    if (lane < 10) {
        float acc = bm[lane];
        for (int k = 0; k < HH; ++k) acc = fmaf(semb[k], Wm[k * 10 + lane], acc);
        slog[lane] = acc;
    }
    __syncthreads();
    if (lane < 10) {
        float mx = -1e30f;
        for (int j = 0; j < 10; ++j) mx = fmaxf(mx, slog[j]);
        float den = 0.f;
        for (int j = 0; j < 10; ++j) den += __expf(slog[j] - mx);
        float lg = slog[lane];
        logits[g * 10 + lane] = lg;
        probs[g * 10 + lane] = __expf(lg - mx) / den;
    }
}

// ---------------- launch ----------------

extern "C" void kernel_launch(void* const* d_in, const int* in_sizes, int n_in,
                              void* d_out, int out_size, void* d_ws, size_t ws_size,
                              hipStream_t stream) {
    const float* x     = (const float*)d_in[0];
    const int*   ei    = (const int*)  d_in[1];
    const int*   batch = (const int*)  d_in[2];
    const float* W1 = (const float*)d_in[3];  const float* b1 = (const float*)d_in[4];
    const float* W2 = (const float*)d_in[5];  const float* b2 = (const float*)d_in[6];
    const float* W3 = (const float*)d_in[7];  const float* b3 = (const float*)d_in[8];
    const float* Wm = (const float*)d_in[9];  const float* bm = (const float*)d_in[10];

    const int N = in_sizes[2];
    const int E = in_sizes[1] / 2;
    const int G = (out_size - N * HH) / (2 * 10 + HH);

    const int* row = ei;
    const int* col = ei + E;

    float* out       = (float*)d_out;
    float* logits    = out;
    float* probs     = out + (size_t)G * 10;
    float* node_emb  = out + (size_t)2 * G * 10;
    float* graph_emb = node_emb + (size_t)N * HH;

    char* w = (char*)d_ws;
    auto alloc = [&](size_t bytes) { char* p = w; w += (bytes + 255) & ~(size_t)255; return p; };
    float* dinv    = (float*)alloc((size_t)N * 4);
    int*   cnt     = (int*)  alloc((size_t)N * 4);
    int*   rowptr  = (int*)  alloc(((size_t)N + 1) * 4);
    int*   fill    = (int*)  alloc((size_t)N * 4);
    int*   partial = (int*)  alloc(1024 * 4);
    float* sums    = (float*)alloc((size_t)G * HH * 4 + (size_t)G * 4);  // sums + cnts
    float* cnts    = sums + (size_t)G * HH;
    int*   csr_src = (int*)  alloc((size_t)E * 4);
    float* csr_w   = (float*)alloc((size_t)E * 4);
    float* lin     = (float*)alloc((size_t)N * HH * 4);
    float* hbuf    = (float*)alloc((size_t)N * HH * 4);

    const int B = 256;
    dim3 blk(B);
    int node_blocks = (N + 3) / 4;
    int gemm_blocks = (N + 63) / 64;
    int nB = (N + B - 1) / B;
    int eB = (E + B - 1) / B;
    int scanB = (N + SCAN_B - 1) / SCAN_B;
    int poolN = G * HH + G;
    int pool_blocks = (N + 63) / 64;   // 4 waves/block x 16 nodes/wave

    // CSR build + normalization
    k_zero_int<<<nB, blk, 0, stream>>>(cnt, N);
    k_zero_float<<<(poolN + B - 1) / B, blk, 0, stream>>>(sums, poolN);
    k_count<<<eB, blk, 0, stream>>>(col, E, cnt);
    k_scan_reduce<<<scanB, dim3(SCAN_B), 0, stream>>>(cnt, N, partial);
    k_scan_partials<<<1, dim3(1024), 0, stream>>>(partial, scanB, rowptr, N);
    k_scan_apply<<<scanB, dim3(SCAN_B), 0, stream>>>(cnt, partial, N, rowptr, fill, dinv);
    k_fill<<<eB, blk, 0, stream>>>(row, col, dinv, E, fill, csr_src, csr_w);

    // layer 1 (FIN=128)
    k_gemm2<128><<<gemm_blocks, blk, 0, stream>>>(x, W1, lin, N);
    k_gather<<<node_blocks, blk, 0, stream>>>(lin, csr_src, csr_w, rowptr, dinv, b1, hbuf, N);
    // layer 2
    k_gemm2<64><<<gemm_blocks, blk, 0, stream>>>(hbuf, W2, lin, N);
    k_gather<<<node_blocks, blk, 0, stream>>>(lin, csr_src, csr_w, rowptr, dinv, b2, hbuf, N);
    // layer 3 -> node_emb
    k_gemm2<64><<<gemm_blocks, blk, 0, stream>>>(hbuf, W3, lin, N);
    k_gather<<<node_blocks, blk, 0, stream>>>(lin, csr_src, csr_w, rowptr, dinv, b3, node_emb, N);

    // pool + classifier
    k_pool<<<pool_blocks, blk, 0, stream>>>(node_emb, batch, sums, cnts, N);
    k_final2<<<G, dim3(64), 0, stream>>>(sums, cnts, Wm, bm, logits, probs, graph_emb);
}

// Round 7
// 345.768 us; speedup vs baseline: 2.0417x; 1.0493x over previous
//
#include <hip/hip_runtime.h>
#include <math.h>

#define HH 64
#define SCAN_B 1024

// ---------------- CSR build ----------------

__global__ void k_zero_int(int* __restrict__ p, int n) {
    int i = blockIdx.x * blockDim.x + threadIdx.x;
    if (i < n) p[i] = 0;
}

__global__ void k_zero_float(float* __restrict__ p, int n) {
    int i = blockIdx.x * blockDim.x + threadIdx.x;
    if (i < n) p[i] = 0.f;
}

__global__ void k_count(const int* __restrict__ col, int E, int* __restrict__ cnt) {
    int e = blockIdx.x * blockDim.x + threadIdx.x;
    if (e < E) atomicAdd(&cnt[col[e]], 1);
}

__global__ void k_scan_reduce(const int* __restrict__ cnt, int n, int* __restrict__ partial) {
    int i = blockIdx.x * SCAN_B + threadIdx.x;
    int v = (i < n) ? cnt[i] : 0;
#pragma unroll
    for (int off = 1; off < 64; off <<= 1) v += __shfl_xor(v, off, 64);
    __shared__ int ws[SCAN_B / 64];
    if ((threadIdx.x & 63) == 0) ws[threadIdx.x >> 6] = v;
    __syncthreads();
    if (threadIdx.x == 0) {
        int s = 0;
#pragma unroll
        for (int j = 0; j < SCAN_B / 64; ++j) s += ws[j];
        partial[blockIdx.x] = s;
    }
}

__global__ void k_scan_partials(int* __restrict__ partial, int nb, int* __restrict__ rowptr, int n) {
    __shared__ int buf[1024];
    int tid = threadIdx.x;
    int orig = (tid < nb) ? partial[tid] : 0;
    buf[tid] = orig;
    __syncthreads();
#pragma unroll
    for (int off = 1; off < 1024; off <<= 1) {
        int t = (tid >= off) ? buf[tid - off] : 0;
        __syncthreads();
        buf[tid] += t;
        __syncthreads();
    }
    if (tid < nb) partial[tid] = buf[tid] - orig;
    if (tid == nb - 1) rowptr[n] = buf[tid];
}

__global__ void k_scan_apply(const int* __restrict__ cnt, const int* __restrict__ partial,
                             int n, int* __restrict__ rowptr, int* __restrict__ fill,
                             float* __restrict__ dinv) {
    __shared__ int buf[SCAN_B];
    int tid = threadIdx.x;
    int i = blockIdx.x * SCAN_B + tid;
    int orig = (i < n) ? cnt[i] : 0;
    buf[tid] = orig;
    __syncthreads();
#pragma unroll
    for (int off = 1; off < SCAN_B; off <<= 1) {
        int t = (tid >= off) ? buf[tid - off] : 0;
        __syncthreads();
        buf[tid] += t;
        __syncthreads();
    }
    if (i < n) {
        int excl = buf[tid] - orig + partial[blockIdx.x];
        rowptr[i] = excl;
        fill[i]   = excl;
        dinv[i]   = rsqrtf((float)(orig + 1));
    }
}

// one 8B packed store per edge: {src, bits(dinv[r]*dinv[c])}
__global__ void k_fill(const int* __restrict__ row, const int* __restrict__ col,
                       const float* __restrict__ dinv, int E,
                       int* __restrict__ fill, int2* __restrict__ csr) {
    int e = blockIdx.x * blockDim.x + threadIdx.x;
    if (e >= E) return;
    int r = row[e], c = col[e];
    int dst = atomicAdd(&fill[c], 1);
    float w = dinv[r] * dinv[c];
    csr[dst] = make_int2(r, __float_as_int(w));
}

// ---------------- dense transform: k-chunked register-tiled GEMM ----------------
template<int FIN>
__global__ __launch_bounds__(256, 4) void k_gemm2(const float* __restrict__ x,
                                                  const float* __restrict__ W,
                                                  float* __restrict__ lin, int n) {
    constexpr int KC = 32;
    constexpr int XS = 68;
    __shared__ __align__(16) float Ws[FIN][HH];
    __shared__ __align__(16) float xs_t[KC][XS];
    const int tid = threadIdx.x;
    const int tx = tid & 15;
    const int ty = tid >> 4;
    const int node0 = blockIdx.x * 64;

    for (int i = tid * 4; i < FIN * HH; i += 1024)
        *(float4*)&Ws[0][i] = *(const float4*)&W[i];

    float acc[4][4] = {};

    const int rr0 = tid >> 3;
    const int cc  = (tid & 7) * 4;

    for (int kc = 0; kc < FIN; kc += KC) {
        __syncthreads();
        for (int rr = rr0; rr < 64; rr += 32) {
            float4 v = make_float4(0.f, 0.f, 0.f, 0.f);
            if (node0 + rr < n) v = *(const float4*)&x[(size_t)(node0 + rr) * FIN + kc + cc];
            xs_t[cc + 0][rr] = v.x;
            xs_t[cc + 1][rr] = v.y;
            xs_t[cc + 2][rr] = v.z;
            xs_t[cc + 3][rr] = v.w;
        }
        __syncthreads();
#pragma unroll 4
        for (int k = 0; k < KC; ++k) {
            float4 a4 = *(const float4*)&xs_t[k][ty * 4];
            float4 b4 = *(const float4*)&Ws[kc + k][tx * 4];
            acc[0][0] = fmaf(a4.x, b4.x, acc[0][0]);
            acc[0][1] = fmaf(a4.x, b4.y, acc[0][1]);
            acc[0][2] = fmaf(a4.x, b4.z, acc[0][2]);
            acc[0][3] = fmaf(a4.x, b4.w, acc[0][3]);
            acc[1][0] = fmaf(a4.y, b4.x, acc[1][0]);
            acc[1][1] = fmaf(a4.y, b4.y, acc[1][1]);
            acc[1][2] = fmaf(a4.y, b4.z, acc[1][2]);
            acc[1][3] = fmaf(a4.y, b4.w, acc[1][3]);
            acc[2][0] = fmaf(a4.z, b4.x, acc[2][0]);
            acc[2][1] = fmaf(a4.z, b4.y, acc[2][1]);
            acc[2][2] = fmaf(a4.z, b4.z, acc[2][2]);
            acc[2][3] = fmaf(a4.z, b4.w, acc[2][3]);
            acc[3][0] = fmaf(a4.w, b4.x, acc[3][0]);
            acc[3][1] = fmaf(a4.w, b4.y, acc[3][1]);
            acc[3][2] = fmaf(a4.w, b4.z, acc[3][2]);
            acc[3][3] = fmaf(a4.w, b4.w, acc[3][3]);
        }
    }

#pragma unroll
    for (int i = 0; i < 4; ++i) {
        int node = node0 + ty * 4 + i;
        if (node < n) *(float4*)&lin[(size_t)node * HH + tx * 4] = *(float4*)acc[i];
    }
}

// ---------------- gather aggregation + bias + L2norm + ReLU ----------------
// One wave per node; packed int2 edge entries; 4-way batched row loads for MLP.
__global__ void k_gather(const float* __restrict__ lin, const int2* __restrict__ csr,
                         const int* __restrict__ rowptr,
                         const float* __restrict__ dinv, const float* __restrict__ b,
                         float* __restrict__ hout, int n) {
    int node = blockIdx.x * (blockDim.x >> 6) + (threadIdx.x >> 6);
    int lane = threadIdx.x & 63;
    if (node >= n) return;
    int start = rowptr[node], end = rowptr[node + 1];
    float di = dinv[node];
    float acc0 = di * di * lin[(size_t)node * HH + lane];   // self-loop
    float acc1 = 0.f, acc2 = 0.f, acc3 = 0.f;
    for (int base = start; base < end; base += 64) {
        int m = end - base; if (m > 64) m = 64;
        int2 ev = (base + lane < end) ? csr[base + lane] : make_int2(0, 0);
        int   sv = ev.x;
        float wv = __int_as_float(ev.y);
        int j = 0;
        for (; j + 3 < m; j += 4) {
            int s0 = __shfl(sv, j, 64);     float w0 = __shfl(wv, j, 64);
            int s1 = __shfl(sv, j + 1, 64); float w1 = __shfl(wv, j + 1, 64);
            int s2 = __shfl(sv, j + 2, 64); float w2 = __shfl(wv, j + 2, 64);
            int s3 = __shfl(sv, j + 3, 64); float w3 = __shfl(wv, j + 3, 64);
            float v0 = lin[(size_t)s0 * HH + lane];
            float v1 = lin[(size_t)s1 * HH + lane];
            float v2 = lin[(size_t)s2 * HH + lane];
            float v3 = lin[(size_t)s3 * HH + lane];
            acc0 = fmaf(w0, v0, acc0);
            acc1 = fmaf(w1, v1, acc1);
            acc2 = fmaf(w2, v2, acc2);
            acc3 = fmaf(w3, v3, acc3);
        }
        for (; j < m; ++j) {
            int s0 = __shfl(sv, j, 64); float w0 = __shfl(wv, j, 64);
            acc0 = fmaf(w0, lin[(size_t)s0 * HH + lane], acc0);
        }
    }
    float v = (acc0 + acc1) + (acc2 + acc3);
    v += b[lane];
    float ss = v * v;
#pragma unroll
    for (int off = 1; off < 64; off <<= 1) ss += __shfl_xor(ss, off, 64);
    v = v / fmaxf(sqrtf(ss), 1e-12f);
    hout[(size_t)node * HH + lane] = fmaxf(v, 0.f);
}

// ---------------- pooling: parallel over nodes ----------------
__global__ __launch_bounds__(256) void k_pool(const float* __restrict__ node_emb,
                                              const int* __restrict__ batch,
                                              float* __restrict__ sums,
                                              float* __restrict__ cnts, int n) {
    const int NPW = 16;
    int wave = blockIdx.x * 4 + (threadIdx.x >> 6);
    int lane = threadIdx.x & 63;
    int start = wave * NPW;
    if (start >= n) return;
    int end = start + NPW; if (end > n) end = n;
    int cur = batch[start];
    float acc = 0.f;
    int runlen = 0;
    for (int node = start; node < end; ++node) {
        int g = batch[node];
        if (g != cur) {
            atomicAdd(&sums[(size_t)cur * HH + lane], acc);
            if (lane == 0) atomicAdd(&cnts[cur], (float)runlen);
            acc = 0.f; runlen = 0; cur = g;
        }
        acc += node_emb[(size_t)node * HH + lane];
        ++runlen;
    }
    atomicAdd(&sums[(size_t)cur * HH + lane], acc);
    if (lane == 0) atomicAdd(&cnts[cur], (float)runlen);
}

// ---------------- classifier + softmax ----------------
__global__ void k_final2(const float* __restrict__ sums, const float* __restrict__ cnts,
                         const float* __restrict__ Wm, const float* __restrict__ bm,
                         float* __restrict__ logits, float* __restrict__ probs,
                         float* __restrict__ graph_emb) {
    int g = blockIdx.x;
    int lane = threadIdx.x;
    float mean = sums[(size_t)g * HH + lane] / fmaxf(cnts[g], 1.0f);
    graph_emb[(size_t)g * HH + lane] = mean;

    __shared__ float semb[HH];
    __shared__ float slog[16];
    semb[lane] = mean;
    __syncthreads();
    if (lane < 10) {
        float acc = bm[lane];
        for (int k = 0; k < HH; ++k) acc = fmaf(semb[k], Wm[k * 10 + lane], acc);
        slog[lane] = acc;
    }
    __syncthreads();
    if (lane < 10) {
        float mx = -1e30f;
        for (int j = 0; j < 10; ++j) mx = fmaxf(mx, slog[j]);
        float den = 0.f;
        for (int j = 0; j < 10; ++j) den += __expf(slog[j] - mx);
        float lg = slog[lane];
        logits[g * 10 + lane] = lg;
        probs[g * 10 + lane] = __expf(lg - mx) / den;
    }
}

// ---------------- launch ----------------

extern "C" void kernel_launch(void* const* d_in, const int* in_sizes, int n_in,
                              void* d_out, int out_size, void* d_ws, size_t ws_size,
                              hipStream_t stream) {
    const float* x     = (const float*)d_in[0];
    const int*   ei    = (const int*)  d_in[1];
    const int*   batch = (const int*)  d_in[2];
    const float* W1 = (const float*)d_in[3];  const float* b1 = (const float*)d_in[4];
    const float* W2 = (const float*)d_in[5];  const float* b2 = (const float*)d_in[6];
    const float* W3 = (const float*)d_in[7];  const float* b3 = (const float*)d_in[8];
    const float* Wm = (const float*)d_in[9];  const float* bm = (const float*)d_in[10];

    const int N = in_sizes[2];
    const int E = in_sizes[1] / 2;
    const int G = (out_size - N * HH) / (2 * 10 + HH);

    const int* row = ei;
    const int* col = ei + E;

    float* out       = (float*)d_out;
    float* logits    = out;
    float* probs     = out + (size_t)G * 10;
    float* node_emb  = out + (size_t)2 * G * 10;
    float* graph_emb = node_emb + (size_t)N * HH;

    char* w = (char*)d_ws;
    auto alloc = [&](size_t bytes) { char* p = w; w += (bytes + 255) & ~(size_t)255; return p; };
    float* dinv    = (float*)alloc((size_t)N * 4);
    int*   cnt     = (int*)  alloc((size_t)N * 4);
    int*   rowptr  = (int*)  alloc(((size_t)N + 1) * 4);
    int*   fill    = (int*)  alloc((size_t)N * 4);
    int*   partial = (int*)  alloc(1024 * 4);
    float* sums    = (float*)alloc((size_t)G * HH * 4 + (size_t)G * 4);  // sums + cnts
    float* cnts    = sums + (size_t)G * HH;
    int2*  csr     = (int2*) alloc((size_t)E * 8);
    float* lin     = (float*)alloc((size_t)N * HH * 4);
    float* hbuf    = (float*)alloc((size_t)N * HH * 4);

    const int B = 256;
    dim3 blk(B);
    int node_blocks = (N + 3) / 4;
    int gemm_blocks = (N + 63) / 64;
    int nB = (N + B - 1) / B;
    int eB = (E + B - 1) / B;
    int scanB = (N + SCAN_B - 1) / SCAN_B;
    int poolN = G * HH + G;
    int pool_blocks = (N + 63) / 64;

    // CSR build + normalization
    k_zero_int<<<nB, blk, 0, stream>>>(cnt, N);
    k_zero_float<<<(poolN + B - 1) / B, blk, 0, stream>>>(sums, poolN);
    k_count<<<eB, blk, 0, stream>>>(col, E, cnt);
    k_scan_reduce<<<scanB, dim3(SCAN_B), 0, stream>>>(cnt, N, partial);
    k_scan_partials<<<1, dim3(1024), 0, stream>>>(partial, scanB, rowptr, N);
    k_scan_apply<<<scanB, dim3(SCAN_B), 0, stream>>>(cnt, partial, N, rowptr, fill, dinv);
    k_fill<<<eB, blk, 0, stream>>>(row, col, dinv, E, fill, csr);

    // layer 1 (FIN=128)
    k_gemm2<128><<<gemm_blocks, blk, 0, stream>>>(x, W1, lin, N);
    k_gather<<<node_blocks, blk, 0, stream>>>(lin, csr, rowptr, dinv, b1, hbuf, N);
    // layer 2
    k_gemm2<64><<<gemm_blocks, blk, 0, stream>>>(hbuf, W2, lin, N);
    k_gather<<<node_blocks, blk, 0, stream>>>(lin, csr, rowptr, dinv, b2, hbuf, N);
    // layer 3 -> node_emb
    k_gemm2<64><<<gemm_blocks, blk, 0, stream>>>(hbuf, W3, lin, N);
    k_gather<<<node_blocks, blk, 0, stream>>>(lin, csr, rowptr, dinv, b3, node_emb, N);

    // pool + classifier
    k_pool<<<pool_blocks, blk, 0, stream>>>(node_emb, batch, sums, cnts, N);
    k_final2<<<G, dim3(64), 0, stream>>>(sums, cnts, Wm, bm, logits, probs, graph_emb);
}